// Round 3
// baseline (65320.087 us; speedup 1.0000x reference)
//
#include <hip/hip_runtime.h>
#include <hip/hip_fp16.h>

typedef unsigned int u32;

#define BATCH 256
#define TSTEPS 1024
#define HDIM 256
#define ODIM 32

// ---------------- workspace layout (bytes) ----------------
// blob: u32 [512][216] per-thread reg weights (mr 64 | mz 64 | mhn 64 | obs 24)
// mxnP: padded M_xn f16 rows, stride 132 u32 (528 B)   -> 135168 B
// woP : padded W_out f16 rows, stride 132 u32          -> 16896 B (32 rows)
// cvec/cvec0: f32 [256][3][256]
#define OFF_BLOB  0u
#define OFF_MXN   442368u
#define OFF_WO    577536u
#define OFF_CVEC  594432u
#define OFF_CVEC0 1380864u
// total 2167296

static __device__ __forceinline__ u32 packh2(float a, float b) {
  __half2 h = __floats2half2_rn(a, b);
  return *reinterpret_cast<u32*>(&h);
}
static __device__ __forceinline__ float mac2(float acc, u32 w, float h0, float h1) {
  const __half2 hh = *reinterpret_cast<const __half2*>(&w);
  const float2 f = __half22float2(hh);
  acc = fmaf(f.x, h0, acc);
  acc = fmaf(f.y, h1, acc);
  return acc;
}

// ---------------------------------------------------------------------------
// k_pack: per-thread register blobs + padded LDS images of M_xn / W_out.
//   thread tid = 2*j + s  (j = hidden unit, s = 128-elem h half)
//   M_r = W_hh_r + W_ihy_r*W_out ; M_z likewise ; M_hn = W_hh_n ;
//   M_xn = W_ihy_n*W_out (fold of y-feedback through the n-gate)
// grid 2 x 256
// ---------------------------------------------------------------------------
__global__ void k_pack(const float* __restrict__ W_ih, const float* __restrict__ W_hh,
                       const float* __restrict__ W_out, u32* __restrict__ blob,
                       u32* __restrict__ mxnP, u32* __restrict__ woP) {
  const int tid = blockIdx.x * 256 + threadIdx.x;  // 0..511
  const int j = tid >> 1, s = tid & 1;
  const int e0 = 128 * s;
  u32* bb = blob + tid * 216;

  for (int k = 0; k < 16; ++k) {
    float vr[8], vz[8], vh[8], vx[8];
#pragma unroll
    for (int q = 0; q < 8; ++q) {
      const int e = e0 + 8 * k + q;
      vr[q] = W_hh[(j)       * HDIM + e];
      vz[q] = W_hh[(256 + j) * HDIM + e];
      vh[q] = W_hh[(512 + j) * HDIM + e];
      vx[q] = 0.f;
    }
#pragma unroll 8
    for (int u = 0; u < 32; ++u) {
      const float ar = W_ih[(j)       * 96 + 32 + u];
      const float az = W_ih[(256 + j) * 96 + 32 + u];
      const float an = W_ih[(512 + j) * 96 + 32 + u];
#pragma unroll
      for (int q = 0; q < 8; ++q) {
        const float wo = W_out[u * HDIM + e0 + 8 * k + q];
        vr[q] = fmaf(ar, wo, vr[q]);
        vz[q] = fmaf(az, wo, vz[q]);
        vx[q] = fmaf(an, wo, vx[q]);
      }
    }
#pragma unroll
    for (int hq = 0; hq < 4; ++hq) {
      bb[      4 * k + hq] = packh2(vr[2 * hq], vr[2 * hq + 1]);
      bb[64  + 4 * k + hq] = packh2(vz[2 * hq], vz[2 * hq + 1]);
      bb[128 + 4 * k + hq] = packh2(vh[2 * hq], vh[2 * hq + 1]);
      mxnP[132 * j + 64 * s + 4 * k + hq] = packh2(vx[2 * hq], vx[2 * hq + 1]);
    }
  }
  // obs-weight fragments: gate g, obs elems 16s .. 16s+15
#pragma unroll
  for (int g = 0; g < 3; ++g)
#pragma unroll
    for (int i = 0; i < 8; ++i)
      bb[192 + 8 * g + i] = packh2(W_ih[(g * 256 + j) * 96 + 16 * s + 2 * i],
                                   W_ih[(g * 256 + j) * 96 + 16 * s + 2 * i + 1]);
  // W_out padded rows
  if (tid < 32) {
    for (int i = 0; i < 128; ++i)
      woP[132 * tid + i] = packh2(W_out[tid * HDIM + 2 * i], W_out[tid * HDIM + 2 * i + 1]);
  }
}

// ---------------------------------------------------------------------------
// k_cvec: per-batch constants (r/z/xn), steady-state and t==0 variants.
// ---------------------------------------------------------------------------
__global__ void k_cvec(const float* __restrict__ W_ih, const float* __restrict__ b_ih,
                       const float* __restrict__ b_hh, const float* __restrict__ b_out,
                       const float* __restrict__ z_dyn, const float* __restrict__ init_y,
                       float* __restrict__ cvec, float* __restrict__ cvec0) {
  const int b = blockIdx.x, j = threadIdx.x;
  __shared__ float zs[32], bo[32], y0[32];
  if (j < 32) {
    zs[j] = z_dyn[b * 32 + j];
    bo[j] = b_out[j];
    y0[j] = init_y[b * 32 + j];
  }
  __syncthreads();
#pragma unroll
  for (int q = 0; q < 3; ++q) {
    const int g = q * 256 + j;
    const float base = b_ih[g] + ((q < 2) ? b_hh[g] : 0.f);
    float zd = 0.f, yd = 0.f, y0d = 0.f;
#pragma unroll 8
    for (int u = 0; u < 32; ++u) {
      const float wz = W_ih[g * 96 + 64 + u];
      const float wy = W_ih[g * 96 + 32 + u];
      zd  = fmaf(wz, zs[u], zd);
      yd  = fmaf(wy, bo[u], yd);
      y0d = fmaf(wy, y0[u], y0d);
    }
    cvec [(b * 3 + q) * 256 + j] = base + zd + yd;
    cvec0[(b * 3 + q) * 256 + j] = base + zd + y0d;
  }
}

// ---------------------------------------------------------------------------
// Main persistent GRU. grid 256 (batch), block 512, pinned 2 waves/SIMD
// (VGPR cap 256; weight regs 216 + ~25 live). Thread (j=tid>>1, s=tid&1)
// covers h[128s..128s+127]. M_xn + W_out live in LDS (row stride 528 B:
// 64-lane b128 reads spread across 8 bank groups = BW floor).
// LDS: mxn 135168 | wo 16896 | h 1024 | x 256 | yp 4096 = 157440 B
// ---------------------------------------------------------------------------
#define LDS_MXN 0
#define LDS_WO  135168
#define LDS_H   152064
#define LDS_X   153088
#define LDS_YP  153344
#define LDS_BYTES 157440

__global__ __launch_bounds__(512, 2) void k_gru(
    const float* __restrict__ obs, const u32* __restrict__ blob,
    const uint4* __restrict__ matsrc,  // = ws+OFF_MXN (mxnP||woP contiguous)
    const float* __restrict__ cvec, const float* __restrict__ cvec0,
    const float* __restrict__ b_hh, const float* __restrict__ b_out,
    float* __restrict__ out) {
  extern __shared__ char smem[];
  u32*   mxn_s = reinterpret_cast<u32*>(smem + LDS_MXN);
  u32*   wo_s  = reinterpret_cast<u32*>(smem + LDS_WO);
  float* h_s   = reinterpret_cast<float*>(smem + LDS_H);
  float* x_s   = reinterpret_cast<float*>(smem + LDS_X);   // [2][32]
  float* yp_s  = reinterpret_cast<float*>(smem + LDS_YP);  // [2][16][32]

  const int b = blockIdx.x;
  const int tid = threadIdx.x;
  const int j = tid >> 1, s = tid & 1;
  const int o = tid & 31, c = tid >> 5;

  // ---- stage M_xn + W_out into LDS (one contiguous 152064-B copy) ----
  {
    uint4* dst = reinterpret_cast<uint4*>(smem);
    for (int i = tid; i < 9504; i += 512) dst[i] = matsrc[i];
  }

  // ---- per-thread weight regs: 216 u32 (54 uint4) ----
  u32 wb[216];
  {
    const uint4* src = reinterpret_cast<const uint4*>(blob + tid * 216);
#pragma unroll
    for (int i = 0; i < 54; ++i) {
      const uint4 v = src[i];
      wb[4 * i] = v.x; wb[4 * i + 1] = v.y; wb[4 * i + 2] = v.z; wb[4 * i + 3] = v.w;
    }
  }

  const float c_r1 = cvec [(b * 3 + 0) * 256 + j];
  const float c_z1 = cvec [(b * 3 + 1) * 256 + j];
  const float c_n1 = cvec [(b * 3 + 2) * 256 + j];
  const float c_r0 = cvec0[(b * 3 + 0) * 256 + j];
  const float c_z0 = cvec0[(b * 3 + 1) * 256 + j];
  const float c_n0 = cvec0[(b * 3 + 2) * 256 + j];
  const float chn  = b_hh[512 + j];
  const float bo   = (tid < 32) ? b_out[tid] : 0.f;

  const float* obs_b = obs + (size_t)b * TSTEPS * 32;
  float* out_b = out + (size_t)b * TSTEPS * 32;

  const int mb = 132 * j + 64 * s;   // my M_xn slice base (u32 units)
  const int hb = 128 * s;            // my h slice base (f32 units)

  float hreg = 0.f;
  if (tid < 256) h_s[tid] = 0.f;
  if (tid < 32) x_s[tid] = obs_b[tid];
  __syncthreads();

#pragma unroll 1
  for (int t = 0; t < TSTEPS; ++t) {
    const int cur = t & 1;
    float pf = 0.f;
    if (tid < 32) pf = obs_b[(t < TSTEPS - 1 ? t + 1 : t) * 32 + tid];

    const float cr  = t ? c_r1 : c_r0;
    const float cz  = t ? c_z1 : c_z0;
    const float cxn = t ? c_n1 : c_n0;

    float aR = 0.f, aZ = 0.f, aXN = 0.f, aHN = 0.f;
#pragma unroll
    for (int k = 0; k < 16; ++k) {
      const float4 ha = *reinterpret_cast<const float4*>(&h_s[hb + 8 * k]);
      const float4 hc = *reinterpret_cast<const float4*>(&h_s[hb + 8 * k + 4]);
      const uint4  xw = *reinterpret_cast<const uint4*>(&mxn_s[mb + 4 * k]);
      aR  = mac2(aR,  wb[      4 * k],     ha.x, ha.y);
      aR  = mac2(aR,  wb[      4 * k + 1], ha.z, ha.w);
      aR  = mac2(aR,  wb[      4 * k + 2], hc.x, hc.y);
      aR  = mac2(aR,  wb[      4 * k + 3], hc.z, hc.w);
      aZ  = mac2(aZ,  wb[64  + 4 * k],     ha.x, ha.y);
      aZ  = mac2(aZ,  wb[64  + 4 * k + 1], ha.z, ha.w);
      aZ  = mac2(aZ,  wb[64  + 4 * k + 2], hc.x, hc.y);
      aZ  = mac2(aZ,  wb[64  + 4 * k + 3], hc.z, hc.w);
      aHN = mac2(aHN, wb[128 + 4 * k],     ha.x, ha.y);
      aHN = mac2(aHN, wb[128 + 4 * k + 1], ha.z, ha.w);
      aHN = mac2(aHN, wb[128 + 4 * k + 2], hc.x, hc.y);
      aHN = mac2(aHN, wb[128 + 4 * k + 3], hc.z, hc.w);
      aXN = mac2(aXN, xw.x, ha.x, ha.y);
      aXN = mac2(aXN, xw.y, ha.z, ha.w);
      aXN = mac2(aXN, xw.z, hc.x, hc.y);
      aXN = mac2(aXN, xw.w, hc.z, hc.w);
    }
#pragma unroll
    for (int i = 0; i < 4; ++i) {
      const float4 xv = *reinterpret_cast<const float4*>(&x_s[cur * 32 + 16 * s + 4 * i]);
      aR  = mac2(aR,  wb[192 + 2 * i],     xv.x, xv.y);
      aR  = mac2(aR,  wb[192 + 2 * i + 1], xv.z, xv.w);
      aZ  = mac2(aZ,  wb[200 + 2 * i],     xv.x, xv.y);
      aZ  = mac2(aZ,  wb[200 + 2 * i + 1], xv.z, xv.w);
      aXN = mac2(aXN, wb[208 + 2 * i],     xv.x, xv.y);
      aXN = mac2(aXN, wb[208 + 2 * i + 1], xv.z, xv.w);
    }

    // pair reduction (threads 2j, 2j+1 — same wave)
    aR  += __shfl_xor(aR,  1);
    aZ  += __shfl_xor(aZ,  1);
    aHN += __shfl_xor(aHN, 1);
    aXN += __shfl_xor(aXN, 1);

    const float r    = 1.f / (1.f + __expf(-(cr + aR)));
    const float zg   = 1.f / (1.f + __expf(-(cz + aZ)));
    const float pn   = cxn + aXN + r * (chn + aHN);
    const float n    = 1.f - 2.f / (1.f + __expf(2.f * pn));  // tanh
    const float hnew = fmaf(zg, hreg - n, n);
    hreg = hnew;

    __syncthreads();  // A: reads of h_s / x_s[cur] done
    if (s == 0) h_s[j] = hnew;
    if (tid < 32) x_s[(1 - cur) * 32 + tid] = pf;
    if (t > 0 && tid < 32) {  // finalize y_{t-1}
      float y = bo;
#pragma unroll
      for (int ww = 0; ww < 16; ++ww) y += yp_s[(1 - cur) * 512 + ww * 32 + tid];
      out_b[(t - 1) * 32 + tid] = y;
    }
    __syncthreads();  // B: new h visible

    // y partials for h_t: thread (o = tid&31, c = tid>>5) covers h[16c..16c+15]
    {
      const float4 h0 = *reinterpret_cast<const float4*>(&h_s[16 * c]);
      const float4 h1 = *reinterpret_cast<const float4*>(&h_s[16 * c + 4]);
      const float4 h2 = *reinterpret_cast<const float4*>(&h_s[16 * c + 8]);
      const float4 h3 = *reinterpret_cast<const float4*>(&h_s[16 * c + 12]);
      const uint4 w0 = *reinterpret_cast<const uint4*>(&wo_s[132 * o + 8 * c]);
      const uint4 w1 = *reinterpret_cast<const uint4*>(&wo_s[132 * o + 8 * c + 4]);
      float yv = 0.f;
      yv = mac2(yv, w0.x, h0.x, h0.y); yv = mac2(yv, w0.y, h0.z, h0.w);
      yv = mac2(yv, w0.z, h1.x, h1.y); yv = mac2(yv, w0.w, h1.z, h1.w);
      yv = mac2(yv, w1.x, h2.x, h2.y); yv = mac2(yv, w1.y, h2.z, h2.w);
      yv = mac2(yv, w1.z, h3.x, h3.y); yv = mac2(yv, w1.w, h3.z, h3.w);
      yp_s[cur * 512 + c * 32 + o] = yv;
    }
  }

  __syncthreads();
  if (tid < 32) {  // flush y_1023 (TSTEPS-1 is odd -> buffer 1)
    float y = bo;
#pragma unroll
    for (int ww = 0; ww < 16; ++ww) y += yp_s[512 + ww * 32 + tid];
    out_b[(TSTEPS - 1) * 32 + tid] = y;
  }
}

// ---------------------------------------------------------------------------
extern "C" void kernel_launch(void* const* d_in, const int* in_sizes, int n_in,
                              void* d_out, int out_size, void* d_ws, size_t ws_size,
                              hipStream_t stream) {
  (void)in_sizes; (void)n_in; (void)out_size; (void)ws_size;
  const float* init_y  = (const float*)d_in[0];
  const float* obs_seq = (const float*)d_in[1];
  const float* z_dyn   = (const float*)d_in[2];
  const float* W_ih    = (const float*)d_in[3];
  const float* W_hh    = (const float*)d_in[4];
  const float* b_ih    = (const float*)d_in[5];
  const float* b_hh    = (const float*)d_in[6];
  const float* W_out   = (const float*)d_in[7];
  const float* b_out   = (const float*)d_in[8];
  float* out = (float*)d_out;

  char* ws = (char*)d_ws;
  u32*   blob  = (u32*)(ws + OFF_BLOB);
  u32*   mxnP  = (u32*)(ws + OFF_MXN);
  u32*   woP   = (u32*)(ws + OFF_WO);
  float* cvec  = (float*)(ws + OFF_CVEC);
  float* cvec0 = (float*)(ws + OFF_CVEC0);

  hipFuncSetAttribute((const void*)k_gru,
                      hipFuncAttributeMaxDynamicSharedMemorySize, LDS_BYTES);

  k_pack<<<2, 256, 0, stream>>>(W_ih, W_hh, W_out, blob, mxnP, woP);
  k_cvec<<<256, 256, 0, stream>>>(W_ih, b_ih, b_hh, b_out, z_dyn, init_y, cvec, cvec0);
  k_gru<<<BATCH, 512, LDS_BYTES, stream>>>(obs_seq, blob, (const uint4*)(ws + OFF_MXN),
                                           cvec, cvec0, b_hh, b_out, out);
}